// Round 1
// baseline (1298.596 us; speedup 1.0000x reference)
//
#include <hip/hip_runtime.h>

#define B_ 64
#define T_ 256
#define E_ 256
#define H_ 256
#define G4 1024   // 4*H
#define L_ 9

typedef __attribute__((ext_vector_type(8))) short bf16x8;
typedef __attribute__((ext_vector_type(4))) float f32x4;
typedef _Float16 half2v __attribute__((ext_vector_type(2)));

__device__ __forceinline__ ushort f2bf(float x){
  unsigned u = __float_as_uint(x);
  unsigned r = (u + 0x7FFFu + ((u >> 16) & 1u)) >> 16;
  return (ushort)r;
}
__device__ __forceinline__ ushort f2h(float x){
  _Float16 h = (_Float16)x;
  return __builtin_bit_cast(ushort, h);
}
__device__ __forceinline__ float fdot2(unsigned a, unsigned b, float c){
  return __builtin_amdgcn_fdot2(__builtin_bit_cast(half2v, a),
                                __builtin_bit_cast(half2v, b), c, false);
}
__device__ __forceinline__ float fsig(float x){
  return __builtin_amdgcn_rcpf(1.f + __expf(-x));
}
__device__ __forceinline__ float ftanh(float x){
  return 1.f - 2.f * __builtin_amdgcn_rcpf(__expf(2.f * x) + 1.f);
}

// ---------------- seq_lens ----------------
__global__ void k_seqlen(const int* __restrict__ inp, int* __restrict__ lens,
                         float* __restrict__ out_len){
  int b = blockIdx.x, lane = threadIdx.x;
  int c = 0;
  for (int t = lane; t < T_; t += 64) c += (inp[b * T_ + t] != 0);
  for (int off = 32; off; off >>= 1) c += __shfl_xor(c, off);
  if (lane == 0){ lens[b] = c; out_len[b] = (float)c; }
}

// ---------------- W -> bf16, transposed [dir][n][k] ----------------
__global__ void k_cvt_wt(const float* __restrict__ Wf, const float* __restrict__ Wb,
                         ushort* __restrict__ WT){
  int idx = blockIdx.x * 256 + threadIdx.x;       // < 524288
  int dir = idx >> 18; int rem = idx & 262143;
  int n = rem >> 8, k = rem & 255;
  const float* W = dir ? Wb : Wf;
  WT[idx] = f2bf(W[k * G4 + n]);
}

// ---------------- U -> f16 packed [dir][g<32][j<1024][q<4] half2 ----------------
__global__ void k_cvt_upk(const float* __restrict__ Uf, const float* __restrict__ Ub,
                          unsigned* __restrict__ Upk){
  int idx = blockIdx.x * 256 + threadIdx.x;       // < 262144
  int dir = idx >> 17; int rem = idx & 131071;
  int q = rem & 3, j = (rem >> 2) & 1023, g = rem >> 12;
  const float* U = dir ? Ub : Uf;
  int k = 8 * g + 2 * q;
  unsigned p0 = f2h(U[k * G4 + j]);
  unsigned p1 = f2h(U[(k + 1) * G4 + j]);
  Upk[idx] = p0 | (p1 << 16);                      // dst index == idx (q fastest)
}

// ---------------- X = bf16(emb[inp]) ----------------
__global__ void k_gather(const int* __restrict__ inp, const float* __restrict__ emb,
                         ushort* __restrict__ X){
  int idx = blockIdx.x * 256 + threadIdx.x;       // < 524288
  int m = idx >> 5, koff = (idx & 31) * 8;
  int tok = inp[m];
  const float* src = emb + (size_t)tok * E_ + koff;
  float4 a = *(const float4*)src;
  float4 b = *(const float4*)(src + 4);
  uint4 o;
  o.x = (unsigned)f2bf(a.x) | ((unsigned)f2bf(a.y) << 16);
  o.y = (unsigned)f2bf(a.z) | ((unsigned)f2bf(a.w) << 16);
  o.z = (unsigned)f2bf(b.x) | ((unsigned)f2bf(b.y) << 16);
  o.w = (unsigned)f2bf(b.z) | ((unsigned)f2bf(b.w) << 16);
  *(uint4*)(X + m * E_ + koff) = o;
}

// ---------------- Z = X @ W + bias  (bf16 MFMA, 128x128 tile) ----------------
__global__ __launch_bounds__(256) void k_gemm(const ushort* __restrict__ X,
        const ushort* __restrict__ WT, const float* __restrict__ bf_,
        const float* __restrict__ bb_, float* __restrict__ Zf, float* __restrict__ Zb){
  int zi = blockIdx.z;
  const ushort* wt = WT + zi * 262144;
  const float* bias = zi ? bb_ : bf_;
  float* Z = zi ? Zb : Zf;
  int m0 = blockIdx.x * 128, n0 = blockIdx.y * 128;
  __shared__ ushort As[128][40];
  __shared__ ushort Bs[128][40];
  int tid = threadIdx.x;
  int sr = tid >> 1, sk = (tid & 1) * 16;
  const ushort* xg = X + (m0 + sr) * E_ + sk;
  const ushort* wg = wt + (n0 + sr) * E_ + sk;
  f32x4 acc[4][4] = {};
  int lane = tid & 63, wv = tid >> 6;
  int wr = wv >> 1, wc = wv & 1;
  int lrow = lane & 15, kf = (lane >> 4) * 8;
  for (int k0 = 0; k0 < E_; k0 += 32){
    uint4 a0 = *(const uint4*)(xg + k0);
    uint4 a1 = *(const uint4*)(xg + k0 + 8);
    uint4 b0 = *(const uint4*)(wg + k0);
    uint4 b1 = *(const uint4*)(wg + k0 + 8);
    *(uint4*)&As[sr][sk]     = a0;  *(uint4*)&As[sr][sk + 8] = a1;
    *(uint4*)&Bs[sr][sk]     = b0;  *(uint4*)&Bs[sr][sk + 8] = b1;
    __syncthreads();
    bf16x8 af[4], bfr[4];
    #pragma unroll
    for (int i = 0; i < 4; i++) af[i]  = *(const bf16x8*)&As[wr * 64 + i * 16 + lrow][kf];
    #pragma unroll
    for (int i = 0; i < 4; i++) bfr[i] = *(const bf16x8*)&Bs[wc * 64 + i * 16 + lrow][kf];
    #pragma unroll
    for (int i = 0; i < 4; i++)
      #pragma unroll
      for (int j = 0; j < 4; j++)
        acc[i][j] = __builtin_amdgcn_mfma_f32_16x16x32_bf16(af[i], bfr[j], acc[i][j], 0, 0, 0);
    __syncthreads();
  }
  int crow = (lane >> 4) * 4;
  #pragma unroll
  for (int j = 0; j < 4; j++){
    int col = n0 + wc * 64 + j * 16 + lrow;
    float bv = bias[col];
    #pragma unroll
    for (int i = 0; i < 4; i++){
      int rbase = m0 + wr * 64 + i * 16 + crow;
      #pragma unroll
      for (int r = 0; r < 4; r++)
        Z[(size_t)(rbase + r) * G4 + col] = acc[i][j][r] + bv;
    }
  }
}

// ---------------- LSTM recurrence: 1 WG per (batch pair, direction) ----------------
__global__ __launch_bounds__(1024) void k_recur(const float* __restrict__ Zf,
        const float* __restrict__ Zb, const uint4* __restrict__ Upk,
        const int* __restrict__ lens, float* __restrict__ hf, float* __restrict__ hb){
  int bid = blockIdx.x;
  int dir = bid >> 5, pair = bid & 31;
  int b0 = pair * 2, b1 = b0 + 1;
  const float* Zx = dir ? Zb : Zf;
  const uint4* Up = Upk + dir * 32768;
  float* H = dir ? hb : hf;
  __shared__ __align__(16) _Float16 hsh[2][256];
  __shared__ float zsh[2][1024];
  int tid = threadIdx.x;
  if (tid < 256){ hsh[0][tid] = (_Float16)0.f; hsh[1][tid] = (_Float16)0.f; }
  int len0 = lens[b0], len1 = lens[b1];
  float c0 = 0.f, c1 = 0.f, h0v = 0.f, h1v = 0.f;
  __syncthreads();
  const uint4* hp0 = (const uint4*)hsh[0];
  const uint4* hp1 = (const uint4*)hsh[1];
  for (int s = 0; s < T_; ++s){
    int t = dir ? (T_ - 1 - s) : s;
    float za  = Zx[(size_t)(b0 * T_ + t) * G4 + tid];
    float zb2 = Zx[(size_t)(b1 * T_ + t) * G4 + tid];
    float za2 = 0.f, zb3 = 0.f;
    #pragma unroll 8
    for (int g = 0; g < 32; ++g){
      uint4 u  = Up[g * 1024 + tid];
      uint4 ha = hp0[g];
      uint4 hc = hp1[g];
      za  = fdot2(u.x, ha.x, za);   za2 = fdot2(u.y, ha.y, za2);
      za  = fdot2(u.z, ha.z, za);   za2 = fdot2(u.w, ha.w, za2);
      zb2 = fdot2(u.x, hc.x, zb2);  zb3 = fdot2(u.y, hc.y, zb3);
      zb2 = fdot2(u.z, hc.z, zb2);  zb3 = fdot2(u.w, hc.w, zb3);
    }
    zsh[0][tid] = za + za2;
    zsh[1][tid] = zb2 + zb3;
    __syncthreads();
    if (tid < 256){
      {
        float zi = zsh[0][tid], zf2 = zsh[0][tid + 256];
        float zg = zsh[0][tid + 512], zo = zsh[0][tid + 768];
        if (t < len0){
          c0 = fsig(zf2) * c0 + fsig(zi) * ftanh(zg);
          h0v = fsig(zo) * ftanh(c0);
        }
        H[(size_t)(b0 * T_ + t) * H_ + tid] = h0v;
        hsh[0][tid] = (_Float16)h0v;
      }
      {
        float zi = zsh[1][tid], zf2 = zsh[1][tid + 256];
        float zg = zsh[1][tid + 512], zo = zsh[1][tid + 768];
        if (t < len1){
          c1 = fsig(zf2) * c1 + fsig(zi) * ftanh(zg);
          h1v = fsig(zo) * ftanh(c1);
        }
        H[(size_t)(b1 * T_ + t) * H_ + tid] = h1v;
        hsh[1][tid] = (_Float16)h1v;
      }
    }
    __syncthreads();
  }
}

// ---------------- pot = [hf|hb] @ Wd + bd  (one wave per row) ----------------
__global__ __launch_bounds__(256) void k_pot(const float* __restrict__ hf,
        const float* __restrict__ hb, const float* __restrict__ Wd,
        const float* __restrict__ bd, float* __restrict__ out){
  int lane = threadIdx.x & 63, wid = threadIdx.x >> 6;
  int m = blockIdx.x * 4 + wid;
  float4 hfv = *(const float4*)&hf[(size_t)m * H_ + lane * 4];
  float4 hbv = *(const float4*)&hb[(size_t)m * H_ + lane * 4];
  float av[4] = {hfv.x, hfv.y, hfv.z, hfv.w};
  float bv[4] = {hbv.x, hbv.y, hbv.z, hbv.w};
  float acc[9];
  #pragma unroll
  for (int l = 0; l < 9; l++) acc[l] = 0.f;
  #pragma unroll
  for (int i = 0; i < 4; i++){
    int r = lane * 4 + i;
    #pragma unroll
    for (int l = 0; l < 9; l++)
      acc[l] += av[i] * Wd[r * 9 + l] + bv[i] * Wd[(H_ + r) * 9 + l];
  }
  #pragma unroll
  for (int off = 32; off; off >>= 1)
    #pragma unroll
    for (int l = 0; l < 9; l++) acc[l] += __shfl_xor(acc[l], off);
  if (lane == 0){
    #pragma unroll
    for (int l = 0; l < 9; l++) out[(size_t)m * 9 + l] = acc[l] + bd[l];
  }
}

// ---------------- CRF log-likelihood per batch ----------------
__global__ void k_crf(const float* __restrict__ out, const int* __restrict__ tags,
                      const float* __restrict__ trans, const int* __restrict__ lens,
                      float* __restrict__ lln){
  int b = blockIdx.x, lane = threadIdx.x;
  int len = lens[b];
  const float* pot = out + (size_t)b * T_ * 9;
  float up = 0.f, bp = 0.f;
  for (int t = lane; t < T_; t += 64){
    int tg = tags[b * T_ + t];
    if (t < len) up += pot[t * 9 + tg];
    if (t + 1 < len){
      int tg2 = tags[b * T_ + t + 1];
      bp += trans[tg * 9 + tg2];
    }
  }
  for (int off = 32; off; off >>= 1){ up += __shfl_xor(up, off); bp += __shfl_xor(bp, off); }
  float alpha = 0.f;
  if (lane < 9){
    float tr[9];
    #pragma unroll
    for (int i = 0; i < 9; i++) tr[i] = trans[i * 9 + lane];
    alpha = pot[lane];
    for (int t = 1; t < T_; ++t){
      float v[9];
      #pragma unroll
      for (int i = 0; i < 9; i++) v[i] = __shfl(alpha, i) + tr[i];
      float mx = v[0];
      #pragma unroll
      for (int i = 1; i < 9; i++) mx = fmaxf(mx, v[i]);
      float sum = 0.f;
      #pragma unroll
      for (int i = 0; i < 9; i++) sum += __expf(v[i] - mx);
      float an = pot[t * 9 + lane] + mx + __logf(sum);
      if (t < len) alpha = an;
    }
  }
  float mx2 = -3.4e38f;
  for (int i = 0; i < 9; i++){ float a = __shfl(alpha, i); mx2 = fmaxf(mx2, a); }
  float s2 = 0.f;
  for (int i = 0; i < 9; i++){ float a = __shfl(alpha, i); s2 += __expf(a - mx2); }
  float lse = mx2 + __logf(s2);
  if (lane == 0) lln[b] = (up + bp - lse) / (float)len;
}

// ---------------- loss = -mean(ll/len) ----------------
__global__ void k_loss(const float* __restrict__ lln, float* __restrict__ outv){
  int lane = threadIdx.x;
  float v = lln[lane];
  for (int off = 32; off; off >>= 1) v += __shfl_xor(v, off);
  if (lane == 0) outv[0] = -v * (1.f / 64.f);
}

extern "C" void kernel_launch(void* const* d_in, const int* in_sizes, int n_in,
                              void* d_out, int out_size, void* d_ws, size_t ws_size,
                              hipStream_t stream) {
  (void)in_sizes; (void)n_in; (void)out_size; (void)ws_size;
  const int*   inp   = (const int*)  d_in[0];
  const int*   tags  = (const int*)  d_in[1];
  const float* emb   = (const float*)d_in[2];
  const float* Wf    = (const float*)d_in[3];
  const float* Uf    = (const float*)d_in[4];
  const float* bfv   = (const float*)d_in[5];
  const float* Wb    = (const float*)d_in[6];
  const float* Ub    = (const float*)d_in[7];
  const float* bbv   = (const float*)d_in[8];
  const float* Wd    = (const float*)d_in[9];
  const float* bd    = (const float*)d_in[10];
  const float* trans = (const float*)d_in[11];
  float* out = (float*)d_out;

  char* ws = (char*)d_ws;
  float*    Zf   = (float*)   (ws);
  float*    Zb   = (float*)   (ws + 67108864);
  float*    hf   = (float*)   (ws + 134217728);
  float*    hb   = (float*)   (ws + 150994944);
  ushort*   Xbf  = (ushort*)  (ws + 167772160);
  ushort*   WT16 = (ushort*)  (ws + 176160768);
  unsigned* Upk  = (unsigned*)(ws + 177209344);
  int*      lens = (int*)     (ws + 178257920);
  float*    lln  = (float*)   (ws + 178258176);

  k_seqlen<<<64, 64, 0, stream>>>(inp, lens, out + 147456);
  k_cvt_wt<<<2048, 256, 0, stream>>>(Wf, Wb, WT16);
  k_cvt_upk<<<1024, 256, 0, stream>>>(Uf, Ub, Upk);
  k_gather<<<2048, 256, 0, stream>>>(inp, emb, Xbf);
  k_gemm<<<dim3(128, 8, 2), 256, 0, stream>>>(Xbf, WT16, bfv, bbv, Zf, Zb);
  k_recur<<<64, 1024, 0, stream>>>(Zf, Zb, (const uint4*)Upk, lens, hf, hb);
  k_pot<<<4096, 256, 0, stream>>>(hf, hb, Wd, bd, out);
  k_crf<<<64, 64, 0, stream>>>(out, tags, trans, lens, lln);
  k_loss<<<1, 64, 0, stream>>>(lln, out + 147520);
}

// Round 2
// 535.707 us; speedup vs baseline: 2.4241x; 2.4241x over previous
//
#include <hip/hip_runtime.h>

#define B_ 64
#define T_ 256
#define E_ 256
#define H_ 256
#define G4 1024   // 4*H
#define L_ 9
#define SENT 0xFFFFFFFFu

typedef __attribute__((ext_vector_type(8))) short bf16x8;
typedef __attribute__((ext_vector_type(4))) float f32x4;
typedef _Float16 half2v __attribute__((ext_vector_type(2)));

__device__ __forceinline__ ushort f2bf(float x){
  unsigned u = __float_as_uint(x);
  unsigned r = (u + 0x7FFFu + ((u >> 16) & 1u)) >> 16;
  return (ushort)r;
}
__device__ __forceinline__ ushort f2h(float x){
  _Float16 h = (_Float16)x;
  return __builtin_bit_cast(ushort, h);
}
__device__ __forceinline__ float h2lo(unsigned w){
  return (float)__builtin_bit_cast(half2v, w)[0];
}
__device__ __forceinline__ float h2hi(unsigned w){
  return (float)__builtin_bit_cast(half2v, w)[1];
}
__device__ __forceinline__ float fdot2(unsigned a, unsigned b, float c){
  return __builtin_amdgcn_fdot2(__builtin_bit_cast(half2v, a),
                                __builtin_bit_cast(half2v, b), c, false);
}
__device__ __forceinline__ float fsig(float x){
  return __builtin_amdgcn_rcpf(1.f + __expf(-x));
}
__device__ __forceinline__ float ftanh(float x){
  return 1.f - 2.f * __builtin_amdgcn_rcpf(__expf(2.f * x) + 1.f);
}

// ---------------- seq_lens ----------------
__global__ void k_seqlen(const int* __restrict__ inp, int* __restrict__ lens,
                         float* __restrict__ out_len){
  int b = blockIdx.x, lane = threadIdx.x;
  int c = 0;
  for (int t = lane; t < T_; t += 64) c += (inp[b * T_ + t] != 0);
  for (int off = 32; off; off >>= 1) c += __shfl_xor(c, off);
  if (lane == 0){ lens[b] = c; out_len[b] = (float)c; }
}

// ---------------- W -> bf16, transposed [dir][n][k] ----------------
__global__ void k_cvt_wt(const float* __restrict__ Wf, const float* __restrict__ Wb,
                         ushort* __restrict__ WT){
  int idx = blockIdx.x * 256 + threadIdx.x;       // < 524288
  int dir = idx >> 18; int rem = idx & 262143;
  int n = rem >> 8, k = rem & 255;
  const float* W = dir ? Wb : Wf;
  WT[idx] = f2bf(W[k * G4 + n]);
}

// ---------------- U -> f16 packed [dir][col gc][kpair p] half2 ----------------
__global__ void k_cvt_upk2(const float* __restrict__ Uf, const float* __restrict__ Ub,
                           unsigned* __restrict__ Upk2){
  int idx = blockIdx.x * 256 + threadIdx.x;       // < 262144
  int dir = idx >> 17; int rem = idx & 131071;
  int gcol = rem >> 7, p = rem & 127;
  const float* U = dir ? Ub : Uf;
  unsigned lo = f2h(U[(2 * p) * G4 + gcol]);
  unsigned hi = f2h(U[(2 * p + 1) * G4 + gcol]);
  Upk2[idx] = lo | (hi << 16);
}

// ---------------- X = bf16(emb[inp]) ----------------
__global__ void k_gather(const int* __restrict__ inp, const float* __restrict__ emb,
                         ushort* __restrict__ X){
  int idx = blockIdx.x * 256 + threadIdx.x;       // < 524288
  int m = idx >> 5, koff = (idx & 31) * 8;
  int tok = inp[m];
  const float* src = emb + (size_t)tok * E_ + koff;
  float4 a = *(const float4*)src;
  float4 b = *(const float4*)(src + 4);
  uint4 o;
  o.x = (unsigned)f2bf(a.x) | ((unsigned)f2bf(a.y) << 16);
  o.y = (unsigned)f2bf(a.z) | ((unsigned)f2bf(a.w) << 16);
  o.z = (unsigned)f2bf(b.x) | ((unsigned)f2bf(b.y) << 16);
  o.w = (unsigned)f2bf(b.z) | ((unsigned)f2bf(b.w) << 16);
  *(uint4*)(X + m * E_ + koff) = o;
}

// ---------------- Z = X @ W + bias  (bf16 MFMA, 128x128 tile) ----------------
__global__ __launch_bounds__(256) void k_gemm(const ushort* __restrict__ X,
        const ushort* __restrict__ WT, const float* __restrict__ bf_,
        const float* __restrict__ bb_, float* __restrict__ Zf, float* __restrict__ Zb){
  int zi = blockIdx.z;
  const ushort* wt = WT + zi * 262144;
  const float* bias = zi ? bb_ : bf_;
  float* Z = zi ? Zb : Zf;
  int m0 = blockIdx.x * 128, n0 = blockIdx.y * 128;
  __shared__ ushort As[128][40];
  __shared__ ushort Bs[128][40];
  int tid = threadIdx.x;
  int sr = tid >> 1, sk = (tid & 1) * 16;
  const ushort* xg = X + (m0 + sr) * E_ + sk;
  const ushort* wg = wt + (n0 + sr) * E_ + sk;
  f32x4 acc[4][4] = {};
  int lane = tid & 63, wv = tid >> 6;
  int wr = wv >> 1, wc = wv & 1;
  int lrow = lane & 15, kf = (lane >> 4) * 8;
  for (int k0 = 0; k0 < E_; k0 += 32){
    uint4 a0 = *(const uint4*)(xg + k0);
    uint4 a1 = *(const uint4*)(xg + k0 + 8);
    uint4 b0 = *(const uint4*)(wg + k0);
    uint4 b1 = *(const uint4*)(wg + k0 + 8);
    *(uint4*)&As[sr][sk]     = a0;  *(uint4*)&As[sr][sk + 8] = a1;
    *(uint4*)&Bs[sr][sk]     = b0;  *(uint4*)&Bs[sr][sk + 8] = b1;
    __syncthreads();
    bf16x8 af[4], bfr[4];
    #pragma unroll
    for (int i = 0; i < 4; i++) af[i]  = *(const bf16x8*)&As[wr * 64 + i * 16 + lrow][kf];
    #pragma unroll
    for (int i = 0; i < 4; i++) bfr[i] = *(const bf16x8*)&Bs[wc * 64 + i * 16 + lrow][kf];
    #pragma unroll
    for (int i = 0; i < 4; i++)
      #pragma unroll
      for (int j = 0; j < 4; j++)
        acc[i][j] = __builtin_amdgcn_mfma_f32_16x16x32_bf16(af[i], bfr[j], acc[i][j], 0, 0, 0);
    __syncthreads();
  }
  int crow = (lane >> 4) * 4;
  #pragma unroll
  for (int j = 0; j < 4; j++){
    int col = n0 + wc * 64 + j * 16 + lrow;
    float bv = bias[col];
    #pragma unroll
    for (int i = 0; i < 4; i++){
      int rbase = m0 + wr * 64 + i * 16 + crow;
      #pragma unroll
      for (int r = 0; r < 4; r++)
        Z[(size_t)(rbase + r) * G4 + col] = acc[i][j][r] + bv;
    }
  }
}

// ---------------- hbuf sentinel init ----------------
__global__ void k_init_hbuf(uint4* __restrict__ p){
  int i = blockIdx.x * 256 + threadIdx.x;   // < 1048576
  p[i] = uint4{SENT, SENT, SENT, SENT};
}

// ---------------- LSTM recurrence: col-split, U in registers ----------------
// grid 256: bid = s*64 + g, g = dir*32+bg. Peers of a group are 64 apart
// (same XCD under round-robin). 512 threads, 2 batches per WG.
__global__ __launch_bounds__(512, 2) void k_recur2(
    const float* __restrict__ Zf, const float* __restrict__ Zb,
    const unsigned* __restrict__ Upk2, const int* __restrict__ lens,
    ushort* __restrict__ hf16, ushort* __restrict__ hb16,
    unsigned* hbuf){
  int bid = blockIdx.x;
  int g = bid & 63, s = bid >> 6;
  int dir = g >> 5, bg = g & 31;
  int b0 = bg * 2;
  const float* Zx = dir ? Zb : Zf;
  ushort* H = dir ? hb16 : hf16;
  const unsigned* U = Upk2 + dir * 131072;
  unsigned* hg = hbuf + g * 65536;           // [t][256] uints

  int tid = threadIdx.x;
  int lane = tid & 63, wv = tid >> 6;
  int kh = lane >> 5, cl = lane & 31;
  int c_ = wv * 32 + cl;                     // col in slice, 0..255
  int gate = c_ >> 6, jj = c_ & 63;
  int gc = gate * 256 + s * 64 + jj;         // global gate column

  uint4 uu[16];                              // 128 f16 of U column (this k-half)
  {
    const unsigned* up = U + gc * 128 + kh * 64;
    #pragma unroll
    for (int i = 0; i < 16; i++) uu[i] = *(const uint4*)&up[i * 4];
  }

  __shared__ unsigned h_lds[2][128];
  __shared__ float zsh[2][256];

  int ab = tid >> 6, aj = tid & 63;          // activation mapping (tid<128)
  int abb = b0 + (ab & 1);
  int alen = (tid < 128) ? lens[abb] : 0;
  float c_st = 0.f, h_st = 0.f;

  int pt = 0;
  for (int s_ = 0; s_ < 256; ++s_){
    int t = dir ? (255 - s_) : s_;
    // Z prefetch (independent of the exchange -> hides under the spin)
    float z0p = 0.f, z1p = 0.f, z2p = 0.f, z3p = 0.f;
    if (tid < 128){
      const float* zp = Zx + (size_t)(abb * 256 + t) * G4 + s * 64 + aj;
      z0p = zp[0]; z1p = zp[256]; z2p = zp[512]; z3p = zp[768];
    }
    if (s_ == 0){
      if (tid < 256) ((unsigned*)h_lds)[tid] = 0u;
    } else {
      if (tid < 256){
        const unsigned* ap = hg + pt * 256 + tid;
        unsigned w;
        do {
          w = __hip_atomic_load(ap, __ATOMIC_RELAXED, __HIP_MEMORY_SCOPE_AGENT);
        } while (w == SENT);
        ((unsigned*)h_lds)[tid] = w;
      }
    }
    __syncthreads();
    // matvec: z[c_] = sum_k U[k][gc] * h_prev[k], k-half per lane-half
    float a00 = 0.f, a01 = 0.f, a02 = 0.f, a03 = 0.f;
    float a10 = 0.f, a11 = 0.f, a12 = 0.f, a13 = 0.f;
    const unsigned* hl0 = &h_lds[0][kh * 64];
    const unsigned* hl1 = &h_lds[1][kh * 64];
    #pragma unroll
    for (int i = 0; i < 16; i++){
      uint4 h0 = *(const uint4*)&hl0[i * 4];
      uint4 h1 = *(const uint4*)&hl1[i * 4];
      a00 = fdot2(uu[i].x, h0.x, a00);  a01 = fdot2(uu[i].y, h0.y, a01);
      a02 = fdot2(uu[i].z, h0.z, a02);  a03 = fdot2(uu[i].w, h0.w, a03);
      a10 = fdot2(uu[i].x, h1.x, a10);  a11 = fdot2(uu[i].y, h1.y, a11);
      a12 = fdot2(uu[i].z, h1.z, a12);  a13 = fdot2(uu[i].w, h1.w, a13);
    }
    float zd0 = (a00 + a01) + (a02 + a03);
    float zd1 = (a10 + a11) + (a12 + a13);
    zd0 += __shfl_xor(zd0, 32);
    zd1 += __shfl_xor(zd1, 32);
    if (lane < 32){ zsh[0][c_] = zd0; zsh[1][c_] = zd1; }
    __syncthreads();
    if (tid < 128){
      float zi  = z0p + zsh[ab][aj];
      float zf2 = z1p + zsh[ab][64 + aj];
      float zg  = z2p + zsh[ab][128 + aj];
      float zo  = z3p + zsh[ab][192 + aj];
      if (t < alen){
        c_st = fsig(zf2) * c_st + fsig(zi) * ftanh(zg);
        h_st = fsig(zo) * ftanh(c_st);
      }
      unsigned hw = f2h(h_st);
      H[(size_t)(abb * 256 + t) * H_ + s * 64 + aj] = (ushort)hw;
      unsigned other = (unsigned)__shfl_xor((int)hw, 1);
      if ((aj & 1) == 0){
        unsigned word = hw | (other << 16);
        __hip_atomic_store(hg + t * 256 + ab * 128 + s * 32 + (aj >> 1), word,
                           __ATOMIC_RELAXED, __HIP_MEMORY_SCOPE_AGENT);
      }
    }
    __syncthreads();
    pt = t;
  }
}

// ---------------- pot = [hf|hb] @ Wd + bd  (one wave per row, f16 h) ----------------
__global__ __launch_bounds__(256) void k_pot(const ushort* __restrict__ hf16,
        const ushort* __restrict__ hb16, const float* __restrict__ Wd,
        const float* __restrict__ bd, float* __restrict__ out){
  int lane = threadIdx.x & 63, wid = threadIdx.x >> 6;
  int m = blockIdx.x * 4 + wid;
  uint2 ua = *(const uint2*)&hf16[(size_t)m * H_ + lane * 4];
  uint2 ub = *(const uint2*)&hb16[(size_t)m * H_ + lane * 4];
  float av[4] = {h2lo(ua.x), h2hi(ua.x), h2lo(ua.y), h2hi(ua.y)};
  float bv[4] = {h2lo(ub.x), h2hi(ub.x), h2lo(ub.y), h2hi(ub.y)};
  float acc[9];
  #pragma unroll
  for (int l = 0; l < 9; l++) acc[l] = 0.f;
  #pragma unroll
  for (int i = 0; i < 4; i++){
    int r = lane * 4 + i;
    #pragma unroll
    for (int l = 0; l < 9; l++)
      acc[l] += av[i] * Wd[r * 9 + l] + bv[i] * Wd[(H_ + r) * 9 + l];
  }
  #pragma unroll
  for (int off = 32; off; off >>= 1)
    #pragma unroll
    for (int l = 0; l < 9; l++) acc[l] += __shfl_xor(acc[l], off);
  if (lane == 0){
    #pragma unroll
    for (int l = 0; l < 9; l++) out[(size_t)m * 9 + l] = acc[l] + bd[l];
  }
}

// ---------------- CRF log-likelihood per batch ----------------
__global__ void k_crf(const float* __restrict__ out, const int* __restrict__ tags,
                      const float* __restrict__ trans, const int* __restrict__ lens,
                      float* __restrict__ lln){
  int b = blockIdx.x, lane = threadIdx.x;
  int len = lens[b];
  const float* pot = out + (size_t)b * T_ * 9;
  float up = 0.f, bp = 0.f;
  for (int t = lane; t < T_; t += 64){
    int tg = tags[b * T_ + t];
    if (t < len) up += pot[t * 9 + tg];
    if (t + 1 < len){
      int tg2 = tags[b * T_ + t + 1];
      bp += trans[tg * 9 + tg2];
    }
  }
  for (int off = 32; off; off >>= 1){ up += __shfl_xor(up, off); bp += __shfl_xor(bp, off); }
  float alpha = 0.f;
  if (lane < 9){
    float tr[9];
    #pragma unroll
    for (int i = 0; i < 9; i++) tr[i] = trans[i * 9 + lane];
    alpha = pot[lane];
    for (int t = 1; t < T_; ++t){
      float v[9];
      #pragma unroll
      for (int i = 0; i < 9; i++) v[i] = __shfl(alpha, i) + tr[i];
      float mx = v[0];
      #pragma unroll
      for (int i = 1; i < 9; i++) mx = fmaxf(mx, v[i]);
      float sum = 0.f;
      #pragma unroll
      for (int i = 0; i < 9; i++) sum += __expf(v[i] - mx);
      float an = pot[t * 9 + lane] + mx + __logf(sum);
      if (t < len) alpha = an;
    }
  }
  float mx2 = -3.4e38f;
  for (int i = 0; i < 9; i++){ float a = __shfl(alpha, i); mx2 = fmaxf(mx2, a); }
  float s2 = 0.f;
  for (int i = 0; i < 9; i++){ float a = __shfl(alpha, i); s2 += __expf(a - mx2); }
  float lse = mx2 + __logf(s2);
  if (lane == 0) lln[b] = (up + bp - lse) / (float)len;
}

// ---------------- loss = -mean(ll/len) ----------------
__global__ void k_loss(const float* __restrict__ lln, float* __restrict__ outv){
  int lane = threadIdx.x;
  float v = lln[lane];
  for (int off = 32; off; off >>= 1) v += __shfl_xor(v, off);
  if (lane == 0) outv[0] = -v * (1.f / 64.f);
}

extern "C" void kernel_launch(void* const* d_in, const int* in_sizes, int n_in,
                              void* d_out, int out_size, void* d_ws, size_t ws_size,
                              hipStream_t stream) {
  (void)in_sizes; (void)n_in; (void)out_size; (void)ws_size;
  const int*   inp   = (const int*)  d_in[0];
  const int*   tags  = (const int*)  d_in[1];
  const float* emb   = (const float*)d_in[2];
  const float* Wf    = (const float*)d_in[3];
  const float* Uf    = (const float*)d_in[4];
  const float* bfv   = (const float*)d_in[5];
  const float* Wb    = (const float*)d_in[6];
  const float* Ub    = (const float*)d_in[7];
  const float* bbv   = (const float*)d_in[8];
  const float* Wd    = (const float*)d_in[9];
  const float* bd    = (const float*)d_in[10];
  const float* trans = (const float*)d_in[11];
  float* out = (float*)d_out;

  char* ws = (char*)d_ws;
  // layout (bytes): total 169,869,312 <= prior-proven 178 MB
  unsigned* Upk2 = (unsigned*)(ws);                 // 1 MB
  int*      lens = (int*)     (ws + 1048576);       // 256 B
  float*    lln  = (float*)   (ws + 1048832);       // 256 B
  ushort*   Xbf  = (ushort*)  (ws + 2097152);       // 8 MB (dead after gemm)
  ushort*   WT16 = (ushort*)  (ws + 10485760);      // 1 MB (dead after gemm)
  unsigned* hbuf = (unsigned*)(ws + 2097152);       // 16 MB, ALIASES Xbf+WT16
  float*    Zf   = (float*)   (ws + 18874368);      // 64 MB
  float*    Zb   = (float*)   (ws + 85983232);      // 64 MB
  ushort*   hf16 = (ushort*)  (ws + 153092096);     // 8 MB
  ushort*   hb16 = (ushort*)  (ws + 161480704);     // 8 MB

  k_seqlen<<<64, 64, 0, stream>>>(inp, lens, out + 147456);
  k_cvt_wt<<<2048, 256, 0, stream>>>(Wf, Wb, WT16);
  k_cvt_upk2<<<1024, 256, 0, stream>>>(Uf, Ub, Upk2);
  k_gather<<<2048, 256, 0, stream>>>(inp, emb, Xbf);
  k_gemm<<<dim3(128, 8, 2), 256, 0, stream>>>(Xbf, WT16, bfv, bbv, Zf, Zb);
  k_init_hbuf<<<4096, 256, 0, stream>>>((uint4*)hbuf);   // after gemm (alias)
  k_recur2<<<256, 512, 0, stream>>>(Zf, Zb, Upk2, lens, hf16, hb16, hbuf);
  k_pot<<<4096, 256, 0, stream>>>(hf16, hb16, Wd, bd, out);
  k_crf<<<64, 64, 0, stream>>>(out, tags, trans, lens, lln);
  k_loss<<<1, 64, 0, stream>>>(lln, out + 147520);
}